// Round 1
// baseline (676.322 us; speedup 1.0000x reference)
//
#include <hip/hip_runtime.h>
#include <hip/hip_bf16.h>
#include <stdint.h>

typedef __bf16 bf16x8 __attribute__((ext_vector_type(8)));
typedef float f32x4 __attribute__((ext_vector_type(4)));
typedef unsigned short ushort_t;

#define MFMA16 __builtin_amdgcn_mfma_f32_16x16x32_bf16

static constexpr int Bc = 2, Sc = 2048, Ec = 2048, Hc = 16;

__device__ __forceinline__ void gload16(const void* g, void* l) {
  __builtin_amdgcn_global_load_lds(
      (const __attribute__((address_space(1))) void*)g,
      (__attribute__((address_space(3))) void*)l, 16, 0, 0);
}

// float -> bf16 RNE, bit-level (no header dependency on __hip_bfloat16 internals)
__device__ __forceinline__ ushort_t f2bf(float f) {
  uint32_t u = __float_as_uint(f);
  uint32_t r = (u + 0x7fffu + ((u >> 16) & 1u)) >> 16;
  return (ushort_t)r;
}

// ---------------- elementwise casts ----------------
__global__ void cast_kernel(const float* __restrict__ in, ushort_t* __restrict__ out, int n4) {
  int i = blockIdx.x * 256 + threadIdx.x;
  if (i >= n4) return;
  float4 v = ((const float4*)in)[i];
  ushort4 o;
  o.x = f2bf(v.x); o.y = f2bf(v.y); o.z = f2bf(v.z); o.w = f2bf(v.w);
  ((ushort4*)out)[i] = o;
}

__global__ void cast_pad_kernel(const float* __restrict__ in, ushort_t* __restrict__ out,
                                int rows_in, int cols, int n4) {
  int i = blockIdx.x * 256 + threadIdx.x;
  if (i >= n4) return;
  int c4 = cols >> 2;
  int row = i / c4, col4 = i - row * c4;
  ushort4 o;
  if (row < rows_in) {
    float4 v = ((const float4*)in)[row * c4 + col4];
    o.x = f2bf(v.x); o.y = f2bf(v.y); o.z = f2bf(v.z); o.w = f2bf(v.w);
  } else {
    o.x = 0; o.y = 0; o.z = 0; o.w = 0;
  }
  ((ushort4*)out)[i] = o;
}

// ---------------- GEMM: C[m][n] = sum_k A[m][k]*B[n][k], 128x128x32 tiles ----------------
// MODE 0: store bf16 to Cout (ldc). MODE 2: store f32. MODE 1: scatter kv_exp -> vbuf/kbuf.
template<int MODE>
__global__ __launch_bounds__(256, 2)
void gemm_bt(const ushort_t* __restrict__ A, int lda,
             const ushort_t* __restrict__ Bm, int ldb,
             void* __restrict__ Cout, int ldc,
             int M, int N, int K,
             ushort_t* __restrict__ vbuf, char* __restrict__ kbuf)
{
  __shared__ __align__(16) ushort_t sA[128 * 32];
  __shared__ __align__(16) ushort_t sB[128 * 32];
  int tid = threadIdx.x;
  int nTn = N >> 7;
  int tm = blockIdx.x / nTn, tn = blockIdx.x - tm * nTn;
  int wave = tid >> 6, lane = tid & 63;
  int wm = (wave >> 1) << 6, wn = (wave & 1) << 6;
  int l16 = lane & 15, g16 = lane >> 4;
  f32x4 acc[4][4] = {};
  int srow = tid >> 2, scol = (tid & 3) << 3;
  const ushort_t* Ag = A + (size_t)(tm * 128 + srow) * lda + scol;
  const ushort_t* Bg = Bm + (size_t)(tn * 128 + srow) * ldb + scol;
  ushort_t* sAp = &sA[srow * 32 + scol];
  ushort_t* sBp = &sB[srow * 32 + scol];
  for (int kt = 0; kt < K; kt += 32) {
    gload16(Ag, sAp);
    gload16(Ag + (size_t)64 * lda, sAp + 64 * 32);
    gload16(Bg, sBp);
    gload16(Bg + (size_t)64 * ldb, sBp + 64 * 32);
    Ag += 32; Bg += 32;
    __syncthreads();
    bf16x8 af[4], bfr[4];
#pragma unroll
    for (int i = 0; i < 4; i++) af[i] = *(const bf16x8*)&sA[(wm + i * 16 + l16) * 32 + g16 * 8];
#pragma unroll
    for (int i = 0; i < 4; i++) bfr[i] = *(const bf16x8*)&sB[(wn + i * 16 + l16) * 32 + g16 * 8];
#pragma unroll
    for (int i = 0; i < 4; i++)
#pragma unroll
      for (int j = 0; j < 4; j++)
        acc[i][j] = MFMA16(af[i], bfr[j], acc[i][j], 0, 0, 0);
    __syncthreads();
  }
  // epilogue: C/D layout col=lane&15, row=(lane>>4)*4+r  [m89-verified]
#pragma unroll
  for (int i = 0; i < 4; i++) {
#pragma unroll
    for (int j = 0; j < 4; j++) {
#pragma unroll
      for (int r = 0; r < 4; r++) {
        int grow = tm * 128 + wm + i * 16 + g16 * 4 + r;
        int gcol = tn * 128 + wn + j * 16 + l16;
        float v = acc[i][j][r];
        if constexpr (MODE == 0) {
          ((ushort_t*)Cout)[(size_t)grow * ldc + gcol] = f2bf(v);
        } else if constexpr (MODE == 2) {
          ((float*)Cout)[(size_t)grow * ldc + gcol] = v;
        } else {
          int h = gcol / 192, jj = gcol - h * 192;
          int b = grow >> 11, s = grow & 2047;
          size_t rowb = (size_t)(b * Hc + h) * Sc + s;
          if (jj < 128) {
            vbuf[rowb * 128 + jj] = f2bf(v);
          } else {
            int col = 64 + (jj - 128);                    // nope -> k dims 64..127
            *(ushort_t*)(kbuf + rowb * 256 + ((2 * col) ^ ((s & 7) << 4))) = f2bf(v);
          }
        }
      }
    }
  }
}

// ---------------- broadcast k_rope into kbuf (swizzled byte layout) ----------------
__global__ void rope_fill(const ushort_t* __restrict__ comp, char* __restrict__ kbuf) {
  int i = blockIdx.x * 256 + threadIdx.x;  // over B*S*8 16-byte blocks
  if (i >= Bc * Sc * 8) return;
  int blk = i & 7;
  int m = i >> 3;
  int s = m & 2047, b = m >> 11;
  uint4 v = *(const uint4*)&comp[(size_t)m * 640 + 512 + blk * 8];
  int off = (blk * 16) ^ ((s & 7) << 4);
#pragma unroll
  for (int h = 0; h < Hc; h++) {
    *(uint4*)(kbuf + ((size_t)(b * Hc + h) * Sc + s) * 256 + off) = v;
  }
}

// ---------------- flash attention: 1 block = (b,h,qtile of 128 rows), 4 waves x 32 rows ----------------
__global__ __launch_bounds__(256, 2)
void attn_kernel(const ushort_t* __restrict__ qb, const char* __restrict__ kbuf,
                 const ushort_t* __restrict__ vbuf, const float* __restrict__ mask,
                 ushort_t* __restrict__ attn_o)
{
  __shared__ __align__(16) char smem[65536];
  char* sK = smem;            // 32KB K tile (swizzled); overlaid by P after scores
  char* sV = smem + 32768;    // 32KB V^T tile (swizzled)
  const float scale = 0.08838834764831845f;  // 128^-0.5
  int bid = blockIdx.x;
  int qt = bid & 15, bh = bid >> 4;
  int b = bh >> 4, h = bh & 15;
  int tid = threadIdx.x, wave = tid >> 6, lane = tid & 63;
  int l16 = lane & 15, g16 = lane >> 4;

  // Q fragments in registers for the whole kernel
  bf16x8 qf[2][4];
#pragma unroll
  for (int mi = 0; mi < 2; mi++) {
    int qrow = qt * 128 + wave * 32 + mi * 16 + l16;
    const ushort_t* qp = qb + (size_t)(b * Sc + qrow) * 2048 + h * 128 + g16 * 8;
#pragma unroll
    for (int kf = 0; kf < 4; kf++) qf[mi][kf] = *(const bf16x8*)(qp + kf * 32);
  }

  float mrun[2][4], lrun[2][4];
#pragma unroll
  for (int mi = 0; mi < 2; mi++)
#pragma unroll
    for (int r = 0; r < 4; r++) { mrun[mi][r] = -3.0e38f; lrun[mi][r] = 0.f; }
  f32x4 acco[2][8] = {};

  const char* kg = kbuf + (size_t)bh * Sc * 256;
  const ushort_t* vg = vbuf + (size_t)bh * Sc * 128;

  for (int kt = 0; kt < 16; kt++) {
    // stage K tile: 32KB linear copy (global bytes pre-swizzled)
#pragma unroll
    for (int it = 0; it < 8; it++)
      gload16(kg + kt * 32768 + it * 4096 + tid * 16, sK + it * 4096 + tid * 16);
    // stage V^T tile: reg-staged transpose, swizzled ds writes
#pragma unroll
    for (int it = 0; it < 8; it++) {
      int r = it * 16 + (tid >> 4);
      int c0 = (tid & 15) << 3;
      bf16x8 v = *(const bf16x8*)(vg + (size_t)(kt * 128 + r) * 128 + c0);
      const ushort_t* vu = (const ushort_t*)&v;
#pragma unroll
      for (int e = 0; e < 8; e++) {
        int c = c0 + e;
        *(ushort_t*)(sV + c * 256 + ((2 * r) ^ ((c & 7) << 4))) = vu[e];
      }
    }
    __syncthreads();

    // scores: sc[mi][ni] = Q(32rows) . K(128)^T
    f32x4 sc[2][8] = {};
#pragma unroll
    for (int ni = 0; ni < 8; ni++) {
#pragma unroll
      for (int kf = 0; kf < 4; kf++) {
        bf16x8 kfr = *(const bf16x8*)(sK + (ni * 16 + l16) * 256 +
                                      ((kf * 64 + g16 * 16) ^ ((l16 & 7) << 4)));
        sc[0][ni] = MFMA16(qf[0][kf], kfr, sc[0][ni], 0, 0, 0);
        sc[1][ni] = MFMA16(qf[1][kf], kfr, sc[1][ni], 0, 0, 0);
      }
    }
    __syncthreads();  // all K reads done; safe to overlay P onto sK

    // online softmax (rows live in 16-lane groups; row = g16*4+r within frag)
#pragma unroll
    for (int mi = 0; mi < 2; mi++) {
      int qrowb = qt * 128 + wave * 32 + mi * 16 + g16 * 4;
#pragma unroll
      for (int r = 0; r < 4; r++) {
        const float* mrow = mask + (size_t)(qrowb + r) * Sc + kt * 128 + l16;
        float pv[8];
        float mx = -3.0e38f;
#pragma unroll
        for (int ni = 0; ni < 8; ni++) {
          float s = sc[mi][ni][r] * scale + mrow[ni * 16];
          pv[ni] = s;
          mx = fmaxf(mx, s);
        }
#pragma unroll
        for (int m2 = 1; m2 < 16; m2 <<= 1) mx = fmaxf(mx, __shfl_xor(mx, m2));
        float mnew = fmaxf(mrun[mi][r], mx);
        float corr = __expf(mrun[mi][r] - mnew);
        int rowl = mi * 16 + g16 * 4 + r;
        char* pbase = sK + wave * 8192 + rowl * 256;
        int sx = (rowl & 7) << 4;
        float rsum = 0.f;
#pragma unroll
        for (int ni = 0; ni < 8; ni++) {
          float p = __expf(pv[ni] - mnew);
          rsum += p;
          int col = ni * 16 + l16;
          *(ushort_t*)(pbase + ((2 * col) ^ sx)) = f2bf(p);
        }
#pragma unroll
        for (int m2 = 1; m2 < 16; m2 <<= 1) rsum += __shfl_xor(rsum, m2);
        lrun[mi][r] = lrun[mi][r] * corr + rsum;
        mrun[mi][r] = mnew;
#pragma unroll
        for (int ni = 0; ni < 8; ni++) acco[mi][ni][r] *= corr;
      }
    }

    // PV: acco += P(32x128) . V(128x128)
#pragma unroll
    for (int kf = 0; kf < 4; kf++) {
      bf16x8 pa[2];
#pragma unroll
      for (int mi = 0; mi < 2; mi++)
        pa[mi] = *(const bf16x8*)(sK + wave * 8192 + (mi * 16 + l16) * 256 +
                                  ((kf * 64 + g16 * 16) ^ ((l16 & 7) << 4)));
#pragma unroll
      for (int ni = 0; ni < 8; ni++) {
        bf16x8 vf = *(const bf16x8*)(sV + (ni * 16 + l16) * 256 +
                                     ((kf * 64 + g16 * 16) ^ ((l16 & 7) << 4)));
        acco[0][ni] = MFMA16(pa[0], vf, acco[0][ni], 0, 0, 0);
        acco[1][ni] = MFMA16(pa[1], vf, acco[1][ni], 0, 0, 0);
      }
    }
    __syncthreads();  // before next tile overwrites sK(=P) and sV
  }

  // epilogue: O = acco / l, store bf16 to [m][h*128+vd]
#pragma unroll
  for (int mi = 0; mi < 2; mi++) {
#pragma unroll
    for (int ni = 0; ni < 8; ni++) {
#pragma unroll
      for (int r = 0; r < 4; r++) {
        int qrow = qt * 128 + wave * 32 + mi * 16 + g16 * 4 + r;
        int col = ni * 16 + l16;
        float o = acco[mi][ni][r] / lrun[mi][r];
        attn_o[(size_t)(b * Sc + qrow) * 2048 + h * 128 + col] = f2bf(o);
      }
    }
  }
}

extern "C" void kernel_launch(void* const* d_in, const int* in_sizes, int n_in,
                              void* d_out, int out_size, void* d_ws, size_t ws_size,
                              hipStream_t stream) {
  const float* x    = (const float*)d_in[0];
  const float* mask = (const float*)d_in[1];
  const float* Wkvd = (const float*)d_in[2];
  const float* Wkvu = (const float*)d_in[3];
  const float* Wq   = (const float*)d_in[4];
  const float* Wout = (const float*)d_in[5];

  char* ws = (char*)d_ws;
  size_t off = 0;
  auto alloc = [&](size_t bytes) { char* p = ws + off; off += (bytes + 255) & ~(size_t)255; return p; };
  ushort_t* xb   = (ushort_t*)alloc((size_t)4096 * 2048 * 2);
  ushort_t* wkvd = (ushort_t*)alloc((size_t)640 * 2048 * 2);
  ushort_t* wq   = (ushort_t*)alloc((size_t)2048 * 2048 * 2);
  ushort_t* wkvu = (ushort_t*)alloc((size_t)3072 * 512 * 2);
  ushort_t* wout = (ushort_t*)alloc((size_t)2048 * 2048 * 2);
  ushort_t* comp = (ushort_t*)alloc((size_t)4096 * 640 * 2);
  ushort_t* qbuf = (ushort_t*)alloc((size_t)4096 * 2048 * 2);
  char*     kbuf = alloc((size_t)Bc * Hc * Sc * 256);
  ushort_t* vbuf = (ushort_t*)alloc((size_t)Bc * Hc * Sc * 128 * 2);
  ushort_t* attn_o = xb;  // xb dead after q-GEMM; reuse

  // casts to bf16
  cast_kernel<<<(2097152 + 255) / 256, 256, 0, stream>>>(x, xb, 2097152);
  cast_pad_kernel<<<(327680 + 255) / 256, 256, 0, stream>>>(Wkvd, wkvd, 576, 2048, 327680);
  cast_kernel<<<(1048576 + 255) / 256, 256, 0, stream>>>(Wq, wq, 1048576);
  cast_kernel<<<(393216 + 255) / 256, 256, 0, stream>>>(Wkvu, wkvu, 393216);
  cast_kernel<<<(1048576 + 255) / 256, 256, 0, stream>>>(Wout, wout, 1048576);

  // compressed = x . W_kv_down^T  (N padded 576->640)
  gemm_bt<0><<<32 * 5, 256, 0, stream>>>(xb, 2048, wkvd, 2048, comp, 640, 4096, 640, 2048, nullptr, nullptr);
  // q = x . W_q^T
  gemm_bt<0><<<32 * 16, 256, 0, stream>>>(xb, 2048, wq, 2048, qbuf, 2048, 4096, 2048, 2048, nullptr, nullptr);
  // kv_exp = kv_c . W_kv_up^T, scattered into vbuf + kbuf(nope, swizzled)
  gemm_bt<1><<<32 * 24, 256, 0, stream>>>(comp, 640, wkvu, 512, nullptr, 0, 4096, 3072, 512, vbuf, kbuf);
  // k_rope broadcast into kbuf (swizzled)
  rope_fill<<<32768 / 256, 256, 0, stream>>>(comp, kbuf);
  // flash attention
  attn_kernel<<<Bc * Hc * 16, 256, 0, stream>>>(qbuf, kbuf, vbuf, mask, attn_o);
  // out = attn . W_out^T (fp32 store)
  gemm_bt<2><<<32 * 16, 256, 0, stream>>>(attn_o, 2048, wout, 2048, d_out, 2048, 4096, 2048, 2048, nullptr, nullptr);
}

// Round 2
// 349.723 us; speedup vs baseline: 1.9339x; 1.9339x over previous
//
#include <hip/hip_runtime.h>
#include <hip/hip_bf16.h>
#include <stdint.h>

typedef __bf16 bf16x8 __attribute__((ext_vector_type(8)));
typedef float f32x4 __attribute__((ext_vector_type(4)));
typedef unsigned short ushort_t;

#define MFMA16 __builtin_amdgcn_mfma_f32_16x16x32_bf16

static constexpr int Bc = 2, Sc = 2048, Ec = 2048, Hc = 16;

__device__ __forceinline__ void gload16(const void* g, void* l) {
  __builtin_amdgcn_global_load_lds(
      (const __attribute__((address_space(1))) void*)g,
      (__attribute__((address_space(3))) void*)l, 16, 0, 0);
}

__device__ __forceinline__ ushort_t f2bf(float f) {
  uint32_t u = __float_as_uint(f);
  uint32_t r = (u + 0x7fffu + ((u >> 16) & 1u)) >> 16;
  return (ushort_t)r;
}
__device__ __forceinline__ float bf2f(ushort_t u) {
  return __uint_as_float((uint32_t)u << 16);
}

// ---------------- elementwise casts ----------------
__global__ void cast_kernel(const float* __restrict__ in, ushort_t* __restrict__ out, int n4) {
  int i = blockIdx.x * 256 + threadIdx.x;
  if (i >= n4) return;
  float4 v = ((const float4*)in)[i];
  ushort4 o;
  o.x = f2bf(v.x); o.y = f2bf(v.y); o.z = f2bf(v.z); o.w = f2bf(v.w);
  ((ushort4*)out)[i] = o;
}

__global__ void cast_pad_kernel(const float* __restrict__ in, ushort_t* __restrict__ out,
                                int rows_in, int cols, int n4) {
  int i = blockIdx.x * 256 + threadIdx.x;
  if (i >= n4) return;
  int c4 = cols >> 2;
  int row = i / c4, col4 = i - row * c4;
  ushort4 o;
  if (row < rows_in) {
    float4 v = ((const float4*)in)[row * c4 + col4];
    o.x = f2bf(v.x); o.y = f2bf(v.y); o.z = f2bf(v.z); o.w = f2bf(v.w);
  } else {
    o.x = 0; o.y = 0; o.z = 0; o.w = 0;
  }
  ((ushort4*)out)[i] = o;
}

// ---------------- mask rearrange: m2[q][kb(32)][l16(16)][ni(4)] bf16 ----------------
__global__ void mask_rearrange(const float* __restrict__ mask, ushort_t* __restrict__ m2) {
  int i = blockIdx.x * 256 + threadIdx.x;   // 2048*32*16 = 1048576
  if (i >= 2048 * 32 * 16) return;
  int q = i >> 9, rest = i & 511, kb = rest >> 4, l16 = rest & 15;
  const float* src = mask + (size_t)q * 2048 + kb * 64 + l16;
  ushort4 o;
  o.x = f2bf(src[0]); o.y = f2bf(src[16]); o.z = f2bf(src[32]); o.w = f2bf(src[48]);
  ((ushort4*)m2)[i] = o;
}

// ---------------- GEMM: C[m][n] = sum_k A[m][k]*B[n][k], 128x128x32 tiles ----------------
// MODE 0: store bf16. MODE 2: store f32. MODE 1: scatter kv_exp -> vT(swizzled)/kbuf(swizzled).
template<int MODE>
__global__ __launch_bounds__(256, 2)
void gemm_bt(const ushort_t* __restrict__ A, int lda,
             const ushort_t* __restrict__ Bm, int ldb,
             void* __restrict__ Cout, int ldc,
             int M, int N, int K,
             char* __restrict__ vtb, char* __restrict__ kbuf)
{
  __shared__ __align__(16) ushort_t sA[128 * 32];
  __shared__ __align__(16) ushort_t sB[128 * 32];
  int tid = threadIdx.x;
  int nTn = N >> 7;
  int tm = blockIdx.x / nTn, tn = blockIdx.x - tm * nTn;
  int wave = tid >> 6, lane = tid & 63;
  int wm = (wave >> 1) << 6, wn = (wave & 1) << 6;
  int l16 = lane & 15, g16 = lane >> 4;
  f32x4 acc[4][4] = {};
  int srow = tid >> 2, scol = (tid & 3) << 3;
  const ushort_t* Ag = A + (size_t)(tm * 128 + srow) * lda + scol;
  const ushort_t* Bg = Bm + (size_t)(tn * 128 + srow) * ldb + scol;
  ushort_t* sAp = &sA[srow * 32 + scol];
  ushort_t* sBp = &sB[srow * 32 + scol];
  for (int kt = 0; kt < K; kt += 32) {
    gload16(Ag, sAp);
    gload16(Ag + (size_t)64 * lda, sAp + 64 * 32);
    gload16(Bg, sBp);
    gload16(Bg + (size_t)64 * ldb, sBp + 64 * 32);
    Ag += 32; Bg += 32;
    __syncthreads();
    bf16x8 af[4], bfr[4];
#pragma unroll
    for (int i = 0; i < 4; i++) af[i] = *(const bf16x8*)&sA[(wm + i * 16 + l16) * 32 + g16 * 8];
#pragma unroll
    for (int i = 0; i < 4; i++) bfr[i] = *(const bf16x8*)&sB[(wn + i * 16 + l16) * 32 + g16 * 8];
#pragma unroll
    for (int i = 0; i < 4; i++)
#pragma unroll
      for (int j = 0; j < 4; j++)
        acc[i][j] = MFMA16(af[i], bfr[j], acc[i][j], 0, 0, 0);
    __syncthreads();
  }
  // epilogue: C/D layout col=lane&15, row=(lane>>4)*4+r
#pragma unroll
  for (int i = 0; i < 4; i++) {
#pragma unroll
    for (int j = 0; j < 4; j++) {
#pragma unroll
      for (int r = 0; r < 4; r++) {
        int grow = tm * 128 + wm + i * 16 + g16 * 4 + r;
        int gcol = tn * 128 + wn + j * 16 + l16;
        float v = acc[i][j][r];
        if constexpr (MODE == 0) {
          ((ushort_t*)Cout)[(size_t)grow * ldc + gcol] = f2bf(v);
        } else if constexpr (MODE == 2) {
          ((float*)Cout)[(size_t)grow * ldc + gcol] = v;
        } else {
          int h = gcol / 192, jj = gcol - h * 192;
          int b = grow >> 11, s = grow & 2047;
          size_t bh = (size_t)(b * Hc + h);
          if (jj < 128) {
            // V^T, pre-swizzled for linear gload16 staging of 64-col tiles:
            // vT[bh][vd=jj][tile s>>6][128B chunk], elem byte (2*(s&63)) ^ ((vd&7)<<4)
            *(ushort_t*)(vtb + bh * 524288 + (size_t)jj * 4096 + ((s >> 6) * 128) +
                         ((2 * (s & 63)) ^ ((jj & 7) << 4))) = f2bf(v);
          } else {
            int col = 64 + (jj - 128);                    // nope -> k dims 64..127
            *(ushort_t*)(kbuf + (bh * Sc + s) * 256 + ((2 * col) ^ ((s & 7) << 4))) = f2bf(v);
          }
        }
      }
    }
  }
}

// ---------------- broadcast k_rope into kbuf (swizzled byte layout) ----------------
__global__ void rope_fill(const ushort_t* __restrict__ comp, char* __restrict__ kbuf) {
  int i = blockIdx.x * 256 + threadIdx.x;  // over B*S*8 16-byte blocks
  if (i >= Bc * Sc * 8) return;
  int blk = i & 7;
  int m = i >> 3;
  int s = m & 2047, b = m >> 11;
  uint4 v = *(const uint4*)&comp[(size_t)m * 640 + 512 + blk * 8];
  int off = (blk * 16) ^ ((s & 7) << 4);
#pragma unroll
  for (int h = 0; h < Hc; h++) {
    *(uint4*)(kbuf + ((size_t)(b * Hc + h) * Sc + s) * 256 + off) = v;
  }
}

// ---------------- flash attention: block = (b,h,qtile of 64 rows), 4 waves x 16 rows ----------------
__global__ __launch_bounds__(256, 4)
void attn_kernel(const ushort_t* __restrict__ qb, const char* __restrict__ kbuf,
                 const char* __restrict__ vtb, const ushort_t* __restrict__ m2,
                 ushort_t* __restrict__ attn_o)
{
  __shared__ __align__(16) char smem[32768];
  char* sK = smem;            // 16KB: 64 k-rows x 256B (swizzled); P overlay (4 waves x 2KB)
  char* sV = smem + 16384;    // 16KB: 128 vd-rows x 128B (swizzled)
  const float scale = 0.08838834764831845f;  // 128^-0.5
  int bid = blockIdx.x;
  bid = (bid & 7) * 128 + (bid >> 3);        // XCD-chunked swizzle (1024 % 8 == 0)
  int qt = bid & 31, bh = bid >> 5;
  int b = bh >> 4, h = bh & 15;
  int tid = threadIdx.x, wave = tid >> 6, lane = tid & 63;
  int l16 = lane & 15, g16 = lane >> 4;

  // Q fragments in registers for the whole kernel (16 rows per wave)
  bf16x8 qf[4];
  {
    int qrow = qt * 64 + wave * 16 + l16;
    const ushort_t* qp = qb + (size_t)(b * Sc + qrow) * 2048 + h * 128 + g16 * 8;
#pragma unroll
    for (int kf = 0; kf < 4; kf++) qf[kf] = *(const bf16x8*)(qp + kf * 32);
  }

  float mrun[4], lrun[4];
#pragma unroll
  for (int r = 0; r < 4; r++) { mrun[r] = -3.0e38f; lrun[r] = 0.f; }
  f32x4 acco[8] = {};

  const char* kg = kbuf + (size_t)bh * Sc * 256;
  const char* vg = vtb + (size_t)bh * 524288;
  char* pB = sK + wave * 2048;

  for (int kt = 0; kt < 32; kt++) {
    // stage K tile: 16KB linear (global bytes pre-swizzled)
#pragma unroll
    for (int it = 0; it < 4; it++)
      gload16(kg + kt * 16384 + it * 4096 + tid * 16, sK + it * 4096 + tid * 16);
    // stage V^T tile: 16KB, per-row 128B chunks (global bytes pre-swizzled)
#pragma unroll
    for (int it = 0; it < 4; it++) {
      int l = it * 4096 + tid * 16;
      int vd = l >> 7, byt = l & 127;
      gload16(vg + (size_t)vd * 4096 + kt * 128 + byt, sV + l);
    }
    __syncthreads();

    // scores: sc[ni] = Q(16 rows) . K(64)^T
    f32x4 sc[4] = {};
    __builtin_amdgcn_s_setprio(1);
#pragma unroll
    for (int ni = 0; ni < 4; ni++) {
#pragma unroll
      for (int kf = 0; kf < 4; kf++) {
        bf16x8 kfr = *(const bf16x8*)(sK + (ni * 16 + l16) * 256 +
                                      ((kf * 64 + g16 * 16) ^ ((l16 & 7) << 4)));
        sc[ni] = MFMA16(qf[kf], kfr, sc[ni], 0, 0, 0);
      }
    }
    __builtin_amdgcn_s_setprio(0);
    __syncthreads();  // all K reads done; safe to overlay P onto sK

    // online softmax (row = g16*4+r within frag, cols = ni*16+l16)
#pragma unroll
    for (int r = 0; r < 4; r++) {
      int q = qt * 64 + wave * 16 + g16 * 4 + r;
      ushort4 mv = ((const ushort4*)m2)[(q * 32 + kt) * 16 + l16];
      float pv[4];
      float mx = -3.0e38f;
      pv[0] = sc[0][r] * scale + bf2f(mv.x);
      pv[1] = sc[1][r] * scale + bf2f(mv.y);
      pv[2] = sc[2][r] * scale + bf2f(mv.z);
      pv[3] = sc[3][r] * scale + bf2f(mv.w);
#pragma unroll
      for (int ni = 0; ni < 4; ni++) mx = fmaxf(mx, pv[ni]);
#pragma unroll
      for (int m = 1; m < 16; m <<= 1) mx = fmaxf(mx, __shfl_xor(mx, m));
      float mnew = fmaxf(mrun[r], mx);
      float corr = __expf(mrun[r] - mnew);
      int rowl = g16 * 4 + r;
      char* pb = pB + rowl * 128;
      int sx = (rowl & 7) << 4;
      float rsum = 0.f;
#pragma unroll
      for (int ni = 0; ni < 4; ni++) {
        float p = __expf(pv[ni] - mnew);
        rsum += p;
        *(ushort_t*)(pb + ((2 * (ni * 16 + l16)) ^ sx)) = f2bf(p);
      }
#pragma unroll
      for (int m = 1; m < 16; m <<= 1) rsum += __shfl_xor(rsum, m);
      lrun[r] = lrun[r] * corr + rsum;
      mrun[r] = mnew;
#pragma unroll
      for (int ni = 0; ni < 8; ni++) acco[ni][r] *= corr;
    }

    // PV: acco += P(16x64) . V(64x128)   (P is wave-private -> no barrier needed)
    __builtin_amdgcn_s_setprio(1);
#pragma unroll
    for (int kf = 0; kf < 2; kf++) {
      bf16x8 pa = *(const bf16x8*)(pB + l16 * 128 +
                                   ((kf * 64 + g16 * 16) ^ ((l16 & 7) << 4)));
#pragma unroll
      for (int ni = 0; ni < 8; ni++) {
        bf16x8 vf = *(const bf16x8*)(sV + (ni * 16 + l16) * 128 +
                                     ((kf * 64 + g16 * 16) ^ ((l16 & 7) << 4)));
        acco[ni] = MFMA16(pa, vf, acco[ni], 0, 0, 0);
      }
    }
    __builtin_amdgcn_s_setprio(0);
    __syncthreads();  // before next tile overwrites sK(=P) and sV
  }

  // epilogue: O = acco / l, store bf16 to [m][h*128+vd]
#pragma unroll
  for (int ni = 0; ni < 8; ni++) {
#pragma unroll
    for (int r = 0; r < 4; r++) {
      int qrow = qt * 64 + wave * 16 + g16 * 4 + r;
      int col = ni * 16 + l16;
      float o = acco[ni][r] / lrun[r];
      attn_o[(size_t)(b * Sc + qrow) * 2048 + h * 128 + col] = f2bf(o);
    }
  }
}

extern "C" void kernel_launch(void* const* d_in, const int* in_sizes, int n_in,
                              void* d_out, int out_size, void* d_ws, size_t ws_size,
                              hipStream_t stream) {
  const float* x    = (const float*)d_in[0];
  const float* mask = (const float*)d_in[1];
  const float* Wkvd = (const float*)d_in[2];
  const float* Wkvu = (const float*)d_in[3];
  const float* Wq   = (const float*)d_in[4];
  const float* Wout = (const float*)d_in[5];

  char* ws = (char*)d_ws;
  size_t off = 0;
  auto alloc = [&](size_t bytes) { char* p = ws + off; off += (bytes + 255) & ~(size_t)255; return p; };
  ushort_t* xb   = (ushort_t*)alloc((size_t)4096 * 2048 * 2);
  ushort_t* wkvd = (ushort_t*)alloc((size_t)640 * 2048 * 2);
  ushort_t* wq   = (ushort_t*)alloc((size_t)2048 * 2048 * 2);
  ushort_t* wkvu = (ushort_t*)alloc((size_t)3072 * 512 * 2);
  ushort_t* wout = (ushort_t*)alloc((size_t)2048 * 2048 * 2);
  ushort_t* comp = (ushort_t*)alloc((size_t)4096 * 640 * 2);
  ushort_t* qbuf = (ushort_t*)alloc((size_t)4096 * 2048 * 2);
  char*     kbuf = alloc((size_t)Bc * Hc * Sc * 256);
  char*     vtb  = alloc((size_t)Bc * Hc * 524288);
  ushort_t* attn_o = xb;   // xb dead after q-GEMM; reuse
  ushort_t* m2 = wq;       // wq dead after q-GEMM; reuse (8MB)

  // casts to bf16
  cast_kernel<<<(2097152 + 255) / 256, 256, 0, stream>>>(x, xb, 2097152);
  cast_pad_kernel<<<(327680 + 255) / 256, 256, 0, stream>>>(Wkvd, wkvd, 576, 2048, 327680);
  cast_kernel<<<(1048576 + 255) / 256, 256, 0, stream>>>(Wq, wq, 1048576);
  cast_kernel<<<(393216 + 255) / 256, 256, 0, stream>>>(Wkvu, wkvu, 393216);
  cast_kernel<<<(1048576 + 255) / 256, 256, 0, stream>>>(Wout, wout, 1048576);

  // compressed = x . W_kv_down^T  (N padded 576->640)
  gemm_bt<0><<<32 * 5, 256, 0, stream>>>(xb, 2048, wkvd, 2048, comp, 640, 4096, 640, 2048, nullptr, nullptr);
  // q = x . W_q^T
  gemm_bt<0><<<32 * 16, 256, 0, stream>>>(xb, 2048, wq, 2048, qbuf, 2048, 4096, 2048, 2048, nullptr, nullptr);
  // mask -> fragment-ordered bf16 (after q-GEMM: m2 overlays wq)
  mask_rearrange<<<4096, 256, 0, stream>>>(mask, m2);
  // kv_exp = kv_c . W_kv_up^T, scattered into vT(swizzled) + kbuf(nope, swizzled)
  gemm_bt<1><<<32 * 24, 256, 0, stream>>>(comp, 640, wkvu, 512, nullptr, 0, 4096, 3072, 512, vtb, kbuf);
  // k_rope broadcast into kbuf (swizzled)
  rope_fill<<<32768 / 256, 256, 0, stream>>>(comp, kbuf);
  // flash attention
  attn_kernel<<<1024, 256, 0, stream>>>(qbuf, kbuf, vtb, m2, attn_o);
  // out = attn . W_out^T (fp32 store)
  gemm_bt<2><<<32 * 16, 256, 0, stream>>>(attn_o, 2048, wout, 2048, d_out, 2048, 4096, 2048, 2048, nullptr, nullptr);
}